// Round 1
// baseline (9586.593 us; speedup 1.0000x reference)
//
#include <hip/hip_runtime.h>

// MeshUnpool: out[b, nf, c] += feat[b, nf, r] * values[b,k] / occ[b, c]
// B=16, NF=256, E=12000, U=24000, NNZ=48000
// Round 1: correctness-first atomic scatter baseline.

#define B_   16
#define NF_  256
#define E_   12000
#define U_   24000
#define NNZ_ 48000

__global__ __launch_bounds__(256) void mesh_unpool_scatter(
    const float* __restrict__ feat,     // [B, NF, E]
    const float* __restrict__ values,   // [B, NNZ]
    const float* __restrict__ occ,      // [B, U]
    const int*   __restrict__ rows,     // [B, NNZ]
    const int*   __restrict__ cols,     // [B, NNZ]
    float*       __restrict__ out)      // [B, NF, U]
{
    const int bk = blockIdx.x;              // 0 .. B*NNZ-1
    const int b  = bk / NNZ_;

    // Per-edge scalars: same address across all lanes -> broadcast loads.
    const int   r = rows[bk];
    const int   c = cols[bk];
    const float v = values[bk] / occ[b * U_ + c];

    const int nf = threadIdx.x;             // 0..255

    // Gather feat[b, nf, r]: stride E between lanes (uncoalesced; fix in R2).
    const float f = feat[(size_t)b * ((size_t)NF_ * E_) + (size_t)nf * E_ + r];

    // Scatter-add out[b, nf, c]: stride U between lanes (uncoalesced; fix in R2).
    atomicAdd(out + (size_t)b * ((size_t)NF_ * U_) + (size_t)nf * U_ + c, f * v);
}

extern "C" void kernel_launch(void* const* d_in, const int* in_sizes, int n_in,
                              void* d_out, int out_size, void* d_ws, size_t ws_size,
                              hipStream_t stream) {
    const float* feat   = (const float*)d_in[0];
    const float* values = (const float*)d_in[1];
    const float* occ    = (const float*)d_in[2];
    const int*   rows   = (const int*)d_in[3];
    const int*   cols   = (const int*)d_in[4];
    float*       out    = (float*)d_out;

    // Output is accumulated into -> must start at zero every call.
    hipMemsetAsync(out, 0, (size_t)out_size * sizeof(float), stream);

    const int nblocks = B_ * NNZ_;          // one block per edge
    mesh_unpool_scatter<<<nblocks, 256, 0, stream>>>(feat, values, occ, rows, cols, out);
}

// Round 2
// 1155.163 us; speedup vs baseline: 8.2989x; 8.2989x over previous
//
#include <hip/hip_runtime.h>

// MeshUnpool: out[b, nf, c] = sum_k feat[b, nf, rows[k]] * values[b,k] / occ[b, cols[k]]
// B=16, NF=256, E=12000, U=24000, NNZ=48000
// Round 2: transpose feat -> counting-sort edges by column -> LDS-tiled
// gather/accumulate, coalesced write-once output.

#define B_   16
#define NF_  256
#define E_   12000
#define U_   24000
#define NNZ_ 48000

#define CT_   64                 // columns per output tile
#define NTILE (U_ / CT_)         // 375 tiles per batch
#define SCAN_N    (B_ * U_)      // 384000 counters
#define SCAN_NBLK (SCAN_N / 1024) // 375 (exact)

// ---------------- ws layout (bytes) ----------------
// featT      : B*E*NF*4        = 196,608,000
// counts     : B*U*4           =   1,536,000
// col_start  : B*U*4           =   1,536,000
// cursor     : B*U*4           =   1,536,000
// block_sums : pad 2048
// edge_list  : B*NNZ*4         =   3,072,000
#define OFF_FEATT   ((size_t)0)
#define OFF_COUNTS  (OFF_FEATT  + (size_t)B_*E_*NF_*4)
#define OFF_START   (OFF_COUNTS + (size_t)B_*U_*4)
#define OFF_CURSOR  (OFF_START  + (size_t)B_*U_*4)
#define OFF_BSUMS   (OFF_CURSOR + (size_t)B_*U_*4)
#define OFF_ELIST   (OFF_BSUMS  + 2048)
#define WS_NEEDED   (OFF_ELIST  + (size_t)B_*NNZ_*4)

// ---------------- 1. feature transpose [B,NF,E] -> [B,E,NF] ----------------
__global__ __launch_bounds__(256) void transpose_feat(
    const float* __restrict__ feat, float* __restrict__ featT)
{
    __shared__ float tile[32][33];
    const int e0  = blockIdx.x * 32;   // E/32 = 375
    const int nf0 = blockIdx.y * 32;   // NF/32 = 8
    const int b   = blockIdx.z;
    const int tx = threadIdx.x, ty = threadIdx.y;   // (32, 8)

#pragma unroll
    for (int j = 0; j < 4; ++j)
        tile[ty + 8*j][tx] =
            feat[((size_t)b*NF_ + (nf0 + ty + 8*j)) * E_ + e0 + tx];
    __syncthreads();
#pragma unroll
    for (int j = 0; j < 4; ++j)
        featT[((size_t)b*E_ + (e0 + ty + 8*j)) * NF_ + nf0 + tx] =
            tile[tx][ty + 8*j];
}

// ---------------- 2. histogram of columns ----------------
__global__ __launch_bounds__(256) void col_histogram(
    const int* __restrict__ cols, int* __restrict__ counts)
{
    const int i = blockIdx.x * 256 + threadIdx.x;   // flat b*NNZ+k
    if (i >= B_ * NNZ_) return;
    const int b = i / NNZ_;
    atomicAdd(&counts[b * U_ + cols[i]], 1);
}

// ---------------- 3. exclusive scan over counts (384000) ----------------
__global__ __launch_bounds__(256) void scan_pass_a(
    const int* __restrict__ counts, int* __restrict__ block_sums)
{
    __shared__ int lds[256];
    const int t = threadIdx.x;
    const int4 v = *(const int4*)(counts + blockIdx.x * 1024 + t * 4);
    lds[t] = v.x + v.y + v.z + v.w;
    __syncthreads();
    for (int off = 128; off > 0; off >>= 1) {
        if (t < off) lds[t] += lds[t + off];
        __syncthreads();
    }
    if (t == 0) block_sums[blockIdx.x] = lds[0];
}

__global__ __launch_bounds__(512) void scan_pass_b(int* __restrict__ block_sums)
{
    __shared__ int lds[512];
    const int t = threadIdx.x;
    const int x = (t < SCAN_NBLK) ? block_sums[t] : 0;
    lds[t] = x;
    __syncthreads();
    for (int off = 1; off < 512; off <<= 1) {
        const int u = (t >= off) ? lds[t - off] : 0;
        __syncthreads();
        lds[t] += u;
        __syncthreads();
    }
    if (t < SCAN_NBLK) block_sums[t] = lds[t] - x;   // exclusive
}

__global__ __launch_bounds__(256) void scan_pass_c(
    const int* __restrict__ counts, const int* __restrict__ block_sums,
    int* __restrict__ col_start, int* __restrict__ cursor)
{
    __shared__ int lds[256];
    const int t = threadIdx.x;
    const int base = blockIdx.x * 1024 + t * 4;
    const int4 v = *(const int4*)(counts + base);
    const int s = v.x + v.y + v.z + v.w;
    lds[t] = s;
    __syncthreads();
    for (int off = 1; off < 256; off <<= 1) {
        const int u = (t >= off) ? lds[t - off] : 0;
        __syncthreads();
        lds[t] += u;
        __syncthreads();
    }
    const int off0 = block_sums[blockIdx.x] + (lds[t] - s);
    int4 w;
    w.x = off0;
    w.y = w.x + v.x;
    w.z = w.y + v.y;
    w.w = w.z + v.z;
    *(int4*)(col_start + base) = w;
    *(int4*)(cursor + base)    = w;
}

// ---------------- 4. scatter edge ids into column-sorted list ----------------
__global__ __launch_bounds__(256) void edge_scatter(
    const int* __restrict__ cols, int* __restrict__ cursor,
    int* __restrict__ edge_list)
{
    const int i = blockIdx.x * 256 + threadIdx.x;   // flat b*NNZ+k
    if (i >= B_ * NNZ_) return;
    const int b = i / NNZ_;
    const int pos = atomicAdd(&cursor[b * U_ + cols[i]], 1);
    edge_list[pos] = i;
}

// ---------------- 5. main: gather + LDS tile accumulate + write-once ----------------
__global__ __launch_bounds__(256) void mesh_unpool_main(
    const float* __restrict__ featT,
    const float* __restrict__ values,
    const float* __restrict__ occ,
    const int*   __restrict__ rows,
    const int*   __restrict__ cols,
    const int*   __restrict__ col_start,
    const int*   __restrict__ counts,
    const int*   __restrict__ edge_list,
    float*       __restrict__ out)
{
    __shared__ float acc[CT_][NF_ + 1];   // +1 pad: conflict-free col reads
    const int tile = blockIdx.x;          // 0 .. B*NTILE-1
    const int b    = tile / NTILE;
    const int c0   = (tile % NTILE) * CT_;
    const int tid  = threadIdx.x;

    for (int i = tid; i < CT_ * (NF_ + 1); i += 256)
        ((float*)acc)[i] = 0.f;
    __syncthreads();

    const int idx0    = b * U_ + c0;
    const int e_begin = col_start[idx0];
    const int e_end   = col_start[idx0 + CT_ - 1] + counts[idx0 + CT_ - 1];
    const float* fT   = featT + (size_t)b * E_ * NF_;
    const float* occb = occ + b * U_;
    const int nf      = tid;

    int e = e_begin;
    for (; e + 3 < e_end; e += 4) {                 // 4 loads in flight
        const int k0 = edge_list[e],     k1 = edge_list[e + 1];
        const int k2 = edge_list[e + 2], k3 = edge_list[e + 3];
        const int ca = cols[k0], cb = cols[k1], cc = cols[k2], cd = cols[k3];
        const int r0 = rows[k0], r1 = rows[k1], r2 = rows[k2], r3 = rows[k3];
        const float v0 = values[k0] / occb[ca];
        const float v1 = values[k1] / occb[cb];
        const float v2 = values[k2] / occb[cc];
        const float v3 = values[k3] / occb[cd];
        const float f0 = fT[(size_t)r0 * NF_ + nf];
        const float f1 = fT[(size_t)r1 * NF_ + nf];
        const float f2 = fT[(size_t)r2 * NF_ + nf];
        const float f3 = fT[(size_t)r3 * NF_ + nf];
        acc[ca - c0][nf] += f0 * v0;
        acc[cb - c0][nf] += f1 * v1;
        acc[cc - c0][nf] += f2 * v2;
        acc[cd - c0][nf] += f3 * v3;
    }
    for (; e < e_end; ++e) {
        const int k = edge_list[e];
        const int c = cols[k], r = rows[k];
        const float v = values[k] / occb[c];
        acc[c - c0][nf] += fT[(size_t)r * NF_ + nf] * v;
    }
    __syncthreads();

    // write out[b, nf, c0 .. c0+63]: each wave writes 64 contiguous floats per nf
    const int c_l  = tid & 63;
    const int nf_b = tid >> 6;
    const size_t ob = (size_t)b * NF_ * U_ + c0 + c_l;
#pragma unroll
    for (int j = 0; j < 64; ++j) {
        const int f = nf_b * 64 + j;
        out[ob + (size_t)f * U_] = acc[c_l][f];
    }
}

// ---------------- fallback (ws too small): R1 atomic scatter ----------------
__global__ __launch_bounds__(256) void mesh_unpool_scatter(
    const float* __restrict__ feat, const float* __restrict__ values,
    const float* __restrict__ occ, const int* __restrict__ rows,
    const int* __restrict__ cols, float* __restrict__ out)
{
    const int bk = blockIdx.x;
    const int b  = bk / NNZ_;
    const int r = rows[bk];
    const int c = cols[bk];
    const float v = values[bk] / occ[b * U_ + c];
    const int nf = threadIdx.x;
    const float f = feat[(size_t)b * ((size_t)NF_ * E_) + (size_t)nf * E_ + r];
    atomicAdd(out + (size_t)b * ((size_t)NF_ * U_) + (size_t)nf * U_ + c, f * v);
}

extern "C" void kernel_launch(void* const* d_in, const int* in_sizes, int n_in,
                              void* d_out, int out_size, void* d_ws, size_t ws_size,
                              hipStream_t stream) {
    const float* feat   = (const float*)d_in[0];
    const float* values = (const float*)d_in[1];
    const float* occ    = (const float*)d_in[2];
    const int*   rows   = (const int*)d_in[3];
    const int*   cols   = (const int*)d_in[4];
    float*       out    = (float*)d_out;

    if (ws_size < WS_NEEDED) {   // deterministic fallback
        hipMemsetAsync(out, 0, (size_t)out_size * sizeof(float), stream);
        mesh_unpool_scatter<<<B_ * NNZ_, 256, 0, stream>>>(
            feat, values, occ, rows, cols, out);
        return;
    }

    char* ws = (char*)d_ws;
    float* featT     = (float*)(ws + OFF_FEATT);
    int*   counts    = (int*)  (ws + OFF_COUNTS);
    int*   col_start = (int*)  (ws + OFF_START);
    int*   cursor    = (int*)  (ws + OFF_CURSOR);
    int*   bsums     = (int*)  (ws + OFF_BSUMS);
    int*   elist     = (int*)  (ws + OFF_ELIST);

    // 1. transpose features
    dim3 tgrid(E_ / 32, NF_ / 32, B_);
    transpose_feat<<<tgrid, dim3(32, 8), 0, stream>>>(feat, featT);

    // 2. histogram
    hipMemsetAsync(counts, 0, (size_t)B_ * U_ * sizeof(int), stream);
    col_histogram<<<(B_ * NNZ_ + 255) / 256, 256, 0, stream>>>(cols, counts);

    // 3. exclusive scan -> col_start (+cursor copy)
    scan_pass_a<<<SCAN_NBLK, 256, 0, stream>>>(counts, bsums);
    scan_pass_b<<<1, 512, 0, stream>>>(bsums);
    scan_pass_c<<<SCAN_NBLK, 256, 0, stream>>>(counts, bsums, col_start, cursor);

    // 4. scatter edge ids (sorted by column)
    edge_scatter<<<(B_ * NNZ_ + 255) / 256, 256, 0, stream>>>(cols, cursor, elist);

    // 5. main accumulate + write-once
    mesh_unpool_main<<<B_ * NTILE, 256, 0, stream>>>(
        featT, values, occ, rows, cols, col_start, counts, elist, out);
}

// Round 3
// 422.166 us; speedup vs baseline: 22.7081x; 2.7363x over previous
//
#include <hip/hip_runtime.h>

// MeshUnpool: out[b, nf, c] = sum_k feat[b, nf, rows[k]] * values[b,k] / occ[b, cols[k]]
// B=16, NF=256, E=12000, U=24000, NNZ=48000
// Round 3: packed pre-scaled edges, column-exclusive waves, reg-float4
// accumulation, write-once LDS (no RMW), float4 transpose.

#define B_   16
#define NF_  256
#define E_   12000
#define U_   24000
#define NNZ_ 48000

#define CT_   32                 // columns per output tile
#define CPW_  8                  // columns per wave (4 waves)
#define NTILE (U_ / CT_)         // 750 tiles per batch
#define PAD_  268                // row stride (floats): 16B-aligned, ~4-way on writeout
#define SCAN_N    (B_ * U_)      // 384000 counters
#define SCAN_NBLK (SCAN_N / 1024) // 375 (exact)

// ---------------- ws layout (bytes) ----------------
#define OFF_FEATT   ((size_t)0)
#define OFF_COUNTS  (OFF_FEATT  + (size_t)B_*E_*NF_*4)
#define OFF_START   (OFF_COUNTS + (size_t)B_*U_*4)
#define OFF_CURSOR  (OFF_START  + (size_t)B_*U_*4)
#define OFF_BSUMS   (OFF_CURSOR + (size_t)B_*U_*4)
#define OFF_PACK    (OFF_BSUMS  + 2048)
#define WS_NEEDED   (OFF_PACK   + (size_t)B_*NNZ_*8)

// ---------------- 1. feature transpose [B,NF,E] -> [B,E,NF], float4 both sides ----
__global__ __launch_bounds__(256) void transpose_feat(
    const float* __restrict__ feat, float* __restrict__ featT)
{
    __shared__ float tile[32][33];       // tile[e_local][nf_local]
    const int e0  = blockIdx.x * 32;     // 375
    const int nf0 = blockIdx.y * 32;     // 8
    const int b   = blockIdx.z;
    const int tx = threadIdx.x;          // 0..7  (float4 along the 32-dim)
    const int ty = threadIdx.y;          // 0..31

    const float4 v = *(const float4*)(
        feat + ((size_t)b*NF_ + (nf0 + ty)) * E_ + e0 + tx*4);
    tile[tx*4 + 0][ty] = v.x;
    tile[tx*4 + 1][ty] = v.y;
    tile[tx*4 + 2][ty] = v.z;
    tile[tx*4 + 3][ty] = v.w;
    __syncthreads();

    float4 w;
    w.x = tile[ty][tx*4 + 0];
    w.y = tile[ty][tx*4 + 1];
    w.z = tile[ty][tx*4 + 2];
    w.w = tile[ty][tx*4 + 3];
    *(float4*)(featT + ((size_t)b*E_ + (e0 + ty)) * NF_ + nf0 + tx*4) = w;
}

// ---------------- 2. histogram of columns ----------------
__global__ __launch_bounds__(256) void col_histogram(
    const int* __restrict__ cols, int* __restrict__ counts)
{
    const int i = blockIdx.x * 256 + threadIdx.x;   // flat b*NNZ+k
    if (i >= B_ * NNZ_) return;
    const int b = i / NNZ_;
    atomicAdd(&counts[b * U_ + cols[i]], 1);
}

// ---------------- 3. exclusive scan over counts (384000) ----------------
__global__ __launch_bounds__(256) void scan_pass_a(
    const int* __restrict__ counts, int* __restrict__ block_sums)
{
    __shared__ int lds[256];
    const int t = threadIdx.x;
    const int4 v = *(const int4*)(counts + blockIdx.x * 1024 + t * 4);
    lds[t] = v.x + v.y + v.z + v.w;
    __syncthreads();
    for (int off = 128; off > 0; off >>= 1) {
        if (t < off) lds[t] += lds[t + off];
        __syncthreads();
    }
    if (t == 0) block_sums[blockIdx.x] = lds[0];
}

__global__ __launch_bounds__(512) void scan_pass_b(int* __restrict__ block_sums)
{
    __shared__ int lds[512];
    const int t = threadIdx.x;
    const int x = (t < SCAN_NBLK) ? block_sums[t] : 0;
    lds[t] = x;
    __syncthreads();
    for (int off = 1; off < 512; off <<= 1) {
        const int u = (t >= off) ? lds[t - off] : 0;
        __syncthreads();
        lds[t] += u;
        __syncthreads();
    }
    if (t < SCAN_NBLK) block_sums[t] = lds[t] - x;   // exclusive
}

__global__ __launch_bounds__(256) void scan_pass_c(
    const int* __restrict__ counts, const int* __restrict__ block_sums,
    int* __restrict__ col_start, int* __restrict__ cursor)
{
    __shared__ int lds[256];
    const int t = threadIdx.x;
    const int base = blockIdx.x * 1024 + t * 4;
    const int4 v = *(const int4*)(counts + base);
    const int s = v.x + v.y + v.z + v.w;
    lds[t] = s;
    __syncthreads();
    for (int off = 1; off < 256; off <<= 1) {
        const int u = (t >= off) ? lds[t - off] : 0;
        __syncthreads();
        lds[t] += u;
        __syncthreads();
    }
    const int off0 = block_sums[blockIdx.x] + (lds[t] - s);
    int4 w;
    w.x = off0;
    w.y = w.x + v.x;
    w.z = w.y + v.y;
    w.w = w.z + v.z;
    *(int4*)(col_start + base) = w;
    *(int4*)(cursor + base)    = w;
}

// ---------------- 4. scatter packed pre-scaled edges, sorted by column --------
__global__ __launch_bounds__(256) void edge_scatter(
    const int* __restrict__ rows, const int* __restrict__ cols,
    const float* __restrict__ values, const float* __restrict__ occ,
    int* __restrict__ cursor, float2* __restrict__ pack)
{
    const int i = blockIdx.x * 256 + threadIdx.x;   // flat b*NNZ+k
    if (i >= B_ * NNZ_) return;
    const int b = i / NNZ_;
    const int c = cols[i];
    const int pos = atomicAdd(&cursor[b * U_ + c], 1);
    pack[pos] = make_float2(__int_as_float(rows[i]), values[i] / occ[b * U_ + c]);
}

// ---------------- 5. main: column-exclusive waves, reg accumulate, write-once LDS
__global__ __launch_bounds__(256) void mesh_unpool_main(
    const float*  __restrict__ featT,
    const float2* __restrict__ pack,
    const int*    __restrict__ col_start,
    const int*    __restrict__ counts,
    float*        __restrict__ out)
{
    __shared__ float acc[CT_][PAD_];      // 34,304 B -> 4 blocks/CU
    const int tile = blockIdx.x;          // 0 .. B*NTILE-1
    const int b    = tile / NTILE;
    const int c0   = (tile % NTILE) * CT_;
    const int wid  = threadIdx.x >> 6;    // 0..3: wave owns cols [wid*8, wid*8+8)
    const int lane = threadIdx.x & 63;    // lane covers nf = 4*lane .. 4*lane+3

    const float* fT   = featT + (size_t)b * E_ * NF_;
    const int   cbase = b * U_ + c0 + wid * CPW_;

    // preload the wave's 8 (start,count) pairs up front
    int s[CPW_], n[CPW_];
#pragma unroll
    for (int cc = 0; cc < CPW_; ++cc) {
        s[cc] = col_start[cbase + cc];
        n[cc] = counts[cbase + cc];
    }

#pragma unroll
    for (int cc = 0; cc < CPW_; ++cc) {
        float4 a = make_float4(0.f, 0.f, 0.f, 0.f);
        for (int i = 0; i < n[cc]; ++i) {
            const float2 p = pack[s[cc] + i];            // broadcast 8B load
            const int    r = __float_as_int(p.x);
            const float  v = p.y;
            const float4 f = *(const float4*)(fT + (size_t)r * NF_ + lane * 4);
            a.x += f.x * v; a.y += f.y * v; a.z += f.z * v; a.w += f.w * v;
        }
        // this wave exclusively owns this column: write once, no RMW, no init
        *(float4*)(&acc[wid * CPW_ + cc][lane * 4]) = a;
    }
    __syncthreads();

    // write out[b, nf, c0..c0+31]: coalesced, once
    const int c_l = threadIdx.x & 31;
    const int g   = threadIdx.x >> 5;     // 8 nf-groups of 32
    const size_t ob = (size_t)b * NF_ * U_ + c0 + c_l;
#pragma unroll
    for (int j = 0; j < 32; ++j) {
        const int f = g * 32 + j;
        out[ob + (size_t)f * U_] = acc[c_l][f];
    }
}

// ---------------- fallback (ws too small): R1 atomic scatter ----------------
__global__ __launch_bounds__(256) void mesh_unpool_scatter(
    const float* __restrict__ feat, const float* __restrict__ values,
    const float* __restrict__ occ, const int* __restrict__ rows,
    const int* __restrict__ cols, float* __restrict__ out)
{
    const int bk = blockIdx.x;
    const int b  = bk / NNZ_;
    const int r = rows[bk];
    const int c = cols[bk];
    const float v = values[bk] / occ[b * U_ + c];
    const int nf = threadIdx.x;
    const float f = feat[(size_t)b * ((size_t)NF_ * E_) + (size_t)nf * E_ + r];
    atomicAdd(out + (size_t)b * ((size_t)NF_ * U_) + (size_t)nf * U_ + c, f * v);
}

extern "C" void kernel_launch(void* const* d_in, const int* in_sizes, int n_in,
                              void* d_out, int out_size, void* d_ws, size_t ws_size,
                              hipStream_t stream) {
    const float* feat   = (const float*)d_in[0];
    const float* values = (const float*)d_in[1];
    const float* occ    = (const float*)d_in[2];
    const int*   rows   = (const int*)d_in[3];
    const int*   cols   = (const int*)d_in[4];
    float*       out    = (float*)d_out;

    if (ws_size < WS_NEEDED) {   // deterministic fallback
        hipMemsetAsync(out, 0, (size_t)out_size * sizeof(float), stream);
        mesh_unpool_scatter<<<B_ * NNZ_, 256, 0, stream>>>(
            feat, values, occ, rows, cols, out);
        return;
    }

    char* ws = (char*)d_ws;
    float*  featT     = (float*) (ws + OFF_FEATT);
    int*    counts    = (int*)   (ws + OFF_COUNTS);
    int*    col_start = (int*)   (ws + OFF_START);
    int*    cursor    = (int*)   (ws + OFF_CURSOR);
    int*    bsums     = (int*)   (ws + OFF_BSUMS);
    float2* pack      = (float2*)(ws + OFF_PACK);

    // 1. transpose features (float4 both sides)
    dim3 tgrid(E_ / 32, NF_ / 32, B_);
    transpose_feat<<<tgrid, dim3(8, 32), 0, stream>>>(feat, featT);

    // 2. histogram
    hipMemsetAsync(counts, 0, (size_t)B_ * U_ * sizeof(int), stream);
    col_histogram<<<(B_ * NNZ_ + 255) / 256, 256, 0, stream>>>(cols, counts);

    // 3. exclusive scan -> col_start (+cursor copy)
    scan_pass_a<<<SCAN_NBLK, 256, 0, stream>>>(counts, bsums);
    scan_pass_b<<<1, 512, 0, stream>>>(bsums);
    scan_pass_c<<<SCAN_NBLK, 256, 0, stream>>>(counts, bsums, col_start, cursor);

    // 4. scatter packed pre-scaled edges
    edge_scatter<<<(B_ * NNZ_ + 255) / 256, 256, 0, stream>>>(
        rows, cols, values, occ, cursor, pack);

    // 5. main accumulate + write-once
    mesh_unpool_main<<<B_ * NTILE, 256, 0, stream>>>(
        featT, pack, col_start, counts, out);
}

// Round 4
// 321.738 us; speedup vs baseline: 29.7963x; 1.3121x over previous
//
#include <hip/hip_runtime.h>

// MeshUnpool: out[b, nf, c] = sum_k feat[b, nf, rows[k]] * values[b,k] / occ[b, cols[k]]
// B=16, NF=256, E=12000, U=24000, NNZ=48000
// Round 4: flattened per-wave edge range with 4-deep pipelined loads,
// column id packed into row word, flush-on-change write-once LDS,
// histogram fused into transpose dispatch.

#define B_   16
#define NF_  256
#define E_   12000
#define U_   24000
#define NNZ_ 48000

#define CT_   32                 // columns per output tile
#define CPW_  8                  // columns per wave (4 waves)
#define NTILE (U_ / CT_)         // 750 tiles per batch
#define PAD_  268                // row stride (floats): 16B-aligned, 4-way max on writeout
#define SCAN_N    (B_ * U_)      // 384000 counters
#define SCAN_NBLK (SCAN_N / 1024) // 375 (exact)

#define TBLK_ (B_ * (NF_ / 32) * (E_ / 32))   // 48000 transpose blocks
#define HBLK_ ((B_ * NNZ_ + 255) / 256)       // 3000 histogram blocks

// ---------------- ws layout (bytes) ----------------
#define OFF_FEATT   ((size_t)0)
#define OFF_COUNTS  (OFF_FEATT  + (size_t)B_*E_*NF_*4)
#define OFF_START   (OFF_COUNTS + (size_t)B_*U_*4)
#define OFF_CURSOR  (OFF_START  + (size_t)B_*U_*4)
#define OFF_BSUMS   (OFF_CURSOR + (size_t)B_*U_*4)
#define OFF_PACK    (OFF_BSUMS  + 2048)
#define WS_NEEDED   (OFF_PACK   + (size_t)B_*NNZ_*8)

// ------- 1+2. fused: feature transpose [B,NF,E]->[B,E,NF]  +  column histogram
__global__ __launch_bounds__(256) void transpose_and_hist(
    const float* __restrict__ feat, float* __restrict__ featT,
    const int* __restrict__ cols, int* __restrict__ counts)
{
    __shared__ float tile[32][33];
    const int id = blockIdx.x;

    if (id >= TBLK_) {                       // histogram part
        const int i = (id - TBLK_) * 256 + threadIdx.x;   // flat b*NNZ+k
        if (i < B_ * NNZ_) {
            const int b = i / NNZ_;
            atomicAdd(&counts[b * U_ + cols[i]], 1);
        }
        return;
    }

    // transpose part
    const int e0  = (id % (E_ / 32)) * 32;
    const int t   = id / (E_ / 32);
    const int nf0 = (t & 7) * 32;
    const int b   = t >> 3;
    const int tx  = threadIdx.x & 7;         // float4 along the 32-dim
    const int ty  = threadIdx.x >> 3;        // 0..31

    const float4 v = *(const float4*)(
        feat + ((size_t)b*NF_ + (nf0 + ty)) * E_ + e0 + tx*4);
    tile[tx*4 + 0][ty] = v.x;
    tile[tx*4 + 1][ty] = v.y;
    tile[tx*4 + 2][ty] = v.z;
    tile[tx*4 + 3][ty] = v.w;
    __syncthreads();

    float4 w;
    w.x = tile[ty][tx*4 + 0];
    w.y = tile[ty][tx*4 + 1];
    w.z = tile[ty][tx*4 + 2];
    w.w = tile[ty][tx*4 + 3];
    *(float4*)(featT + ((size_t)b*E_ + (e0 + ty)) * NF_ + nf0 + tx*4) = w;
}

// ---------------- 3. exclusive scan over counts (384000) ----------------
__global__ __launch_bounds__(256) void scan_pass_a(
    const int* __restrict__ counts, int* __restrict__ block_sums)
{
    __shared__ int lds[256];
    const int t = threadIdx.x;
    const int4 v = *(const int4*)(counts + blockIdx.x * 1024 + t * 4);
    lds[t] = v.x + v.y + v.z + v.w;
    __syncthreads();
    for (int off = 128; off > 0; off >>= 1) {
        if (t < off) lds[t] += lds[t + off];
        __syncthreads();
    }
    if (t == 0) block_sums[blockIdx.x] = lds[0];
}

__global__ __launch_bounds__(512) void scan_pass_b(int* __restrict__ block_sums)
{
    __shared__ int lds[512];
    const int t = threadIdx.x;
    const int x = (t < SCAN_NBLK) ? block_sums[t] : 0;
    lds[t] = x;
    __syncthreads();
    for (int off = 1; off < 512; off <<= 1) {
        const int u = (t >= off) ? lds[t - off] : 0;
        __syncthreads();
        lds[t] += u;
        __syncthreads();
    }
    if (t < SCAN_NBLK) block_sums[t] = lds[t] - x;   // exclusive
}

__global__ __launch_bounds__(256) void scan_pass_c(
    const int* __restrict__ counts, const int* __restrict__ block_sums,
    int* __restrict__ col_start, int* __restrict__ cursor)
{
    __shared__ int lds[256];
    const int t = threadIdx.x;
    const int base = blockIdx.x * 1024 + t * 4;
    const int4 v = *(const int4*)(counts + base);
    const int s = v.x + v.y + v.z + v.w;
    lds[t] = s;
    __syncthreads();
    for (int off = 1; off < 256; off <<= 1) {
        const int u = (t >= off) ? lds[t - off] : 0;
        __syncthreads();
        lds[t] += u;
        __syncthreads();
    }
    const int off0 = block_sums[blockIdx.x] + (lds[t] - s);
    int4 w;
    w.x = off0;
    w.y = w.x + v.x;
    w.z = w.y + v.y;
    w.w = w.z + v.z;
    *(int4*)(col_start + base) = w;
    *(int4*)(cursor + base)    = w;
}

// ------- 4. scatter packed pre-scaled edges (col-local id in bits 14+), sorted
__global__ __launch_bounds__(256) void edge_scatter(
    const int* __restrict__ rows, const int* __restrict__ cols,
    const float* __restrict__ values, const float* __restrict__ occ,
    int* __restrict__ cursor, float2* __restrict__ pack)
{
    const int i = blockIdx.x * 256 + threadIdx.x;   // flat b*NNZ+k
    if (i >= B_ * NNZ_) return;
    const int b = i / NNZ_;
    const int c = cols[i];
    const int pos = atomicAdd(&cursor[b * U_ + c], 1);
    const int w = rows[i] | ((c & (CT_ - 1)) << 14);   // r<16384, c_local<32
    pack[pos] = make_float2(__int_as_float(w), values[i] / occ[b * U_ + c]);
}

// ------- 5. main: flattened wave range, 4-deep pipeline, flush-on-change LDS
__global__ __launch_bounds__(256) void mesh_unpool_main(
    const float*  __restrict__ featT,
    const float2* __restrict__ pack,
    const int*    __restrict__ col_start,
    const int*    __restrict__ counts,
    float*        __restrict__ out)
{
    __shared__ float acc[CT_][PAD_];      // 34,304 B -> 4 blocks/CU
    const int tile = blockIdx.x;          // 0 .. B*NTILE-1
    const int b    = tile / NTILE;
    const int c0   = (tile % NTILE) * CT_;
    const int wid  = threadIdx.x >> 6;    // wave owns block-local cols [wid*8, wid*8+8)
    const int lane = threadIdx.x & 63;    // lane covers nf = 4*lane .. 4*lane+3
    const int nf4  = lane * 4;

    const float* fT   = featT + (size_t)b * E_ * NF_;
    const int   cbase = b * U_ + c0 + wid * CPW_;

    const int e_beg = col_start[cbase];
    const int e_end = col_start[cbase + CPW_ - 1] + counts[cbase + CPW_ - 1];

    float4 a = make_float4(0.f, 0.f, 0.f, 0.f);
    int ccur = wid * CPW_;                // block-local column being accumulated
    const int clast = ccur + CPW_ - 1;

    // flush-on-change step; all control wave-uniform (pack is broadcast)
    auto step = [&](int w, float v, const float4& f) {
        const int cl = w >> 14;           // block-local column (w < 2^19, no sign)
        if (cl != ccur) {
            *(float4*)&acc[ccur][nf4] = a;
            a = make_float4(0.f, 0.f, 0.f, 0.f);
            for (++ccur; ccur < cl; ++ccur)
                *(float4*)&acc[ccur][nf4] = make_float4(0.f, 0.f, 0.f, 0.f);
        }
        a.x += f.x * v; a.y += f.y * v; a.z += f.z * v; a.w += f.w * v;
    };

    int e = e_beg;
    for (; e + 4 <= e_end; e += 4) {      // 4 pack + 4 featT loads in flight
        const float2 p0 = pack[e + 0];
        const float2 p1 = pack[e + 1];
        const float2 p2 = pack[e + 2];
        const float2 p3 = pack[e + 3];
        const int w0 = __float_as_int(p0.x), w1 = __float_as_int(p1.x);
        const int w2 = __float_as_int(p2.x), w3 = __float_as_int(p3.x);
        const float4 f0 = *(const float4*)(fT + (size_t)(w0 & 0x3FFF) * NF_ + nf4);
        const float4 f1 = *(const float4*)(fT + (size_t)(w1 & 0x3FFF) * NF_ + nf4);
        const float4 f2 = *(const float4*)(fT + (size_t)(w2 & 0x3FFF) * NF_ + nf4);
        const float4 f3 = *(const float4*)(fT + (size_t)(w3 & 0x3FFF) * NF_ + nf4);
        step(w0, p0.y, f0);
        step(w1, p1.y, f1);
        step(w2, p2.y, f2);
        step(w3, p3.y, f3);
    }
    for (; e < e_end; ++e) {              // tail
        const float2 p = pack[e];
        const int w = __float_as_int(p.x);
        const float4 f = *(const float4*)(fT + (size_t)(w & 0x3FFF) * NF_ + nf4);
        step(w, p.y, f);
    }
    // final flush + zero-fill remaining owned columns (each col written once)
    *(float4*)&acc[ccur][nf4] = a;
    for (++ccur; ccur <= clast; ++ccur)
        *(float4*)&acc[ccur][nf4] = make_float4(0.f, 0.f, 0.f, 0.f);
    __syncthreads();

    // write out[b, nf, c0..c0+31]: coalesced, once
    const int c_l = threadIdx.x & 31;
    const int g   = threadIdx.x >> 5;     // 8 nf-groups of 32
    const size_t ob = (size_t)b * NF_ * U_ + c0 + c_l;
#pragma unroll
    for (int j = 0; j < 32; ++j) {
        const int f = g * 32 + j;
        out[ob + (size_t)f * U_] = acc[c_l][f];
    }
}

// ---------------- fallback (ws too small): R1 atomic scatter ----------------
__global__ __launch_bounds__(256) void mesh_unpool_scatter(
    const float* __restrict__ feat, const float* __restrict__ values,
    const float* __restrict__ occ, const int* __restrict__ rows,
    const int* __restrict__ cols, float* __restrict__ out)
{
    const int bk = blockIdx.x;
    const int b  = bk / NNZ_;
    const int r = rows[bk];
    const int c = cols[bk];
    const float v = values[bk] / occ[b * U_ + c];
    const int nf = threadIdx.x;
    const float f = feat[(size_t)b * ((size_t)NF_ * E_) + (size_t)nf * E_ + r];
    atomicAdd(out + (size_t)b * ((size_t)NF_ * U_) + (size_t)nf * U_ + c, f * v);
}

extern "C" void kernel_launch(void* const* d_in, const int* in_sizes, int n_in,
                              void* d_out, int out_size, void* d_ws, size_t ws_size,
                              hipStream_t stream) {
    const float* feat   = (const float*)d_in[0];
    const float* values = (const float*)d_in[1];
    const float* occ    = (const float*)d_in[2];
    const int*   rows   = (const int*)d_in[3];
    const int*   cols   = (const int*)d_in[4];
    float*       out    = (float*)d_out;

    if (ws_size < WS_NEEDED) {   // deterministic fallback
        hipMemsetAsync(out, 0, (size_t)out_size * sizeof(float), stream);
        mesh_unpool_scatter<<<B_ * NNZ_, 256, 0, stream>>>(
            feat, values, occ, rows, cols, out);
        return;
    }

    char* ws = (char*)d_ws;
    float*  featT     = (float*) (ws + OFF_FEATT);
    int*    counts    = (int*)   (ws + OFF_COUNTS);
    int*    col_start = (int*)   (ws + OFF_START);
    int*    cursor    = (int*)   (ws + OFF_CURSOR);
    int*    bsums     = (int*)   (ws + OFF_BSUMS);
    float2* pack      = (float2*)(ws + OFF_PACK);

    // 1+2. transpose features + histogram (fused dispatch)
    hipMemsetAsync(counts, 0, (size_t)B_ * U_ * sizeof(int), stream);
    transpose_and_hist<<<TBLK_ + HBLK_, 256, 0, stream>>>(feat, featT, cols, counts);

    // 3. exclusive scan -> col_start (+cursor copy)
    scan_pass_a<<<SCAN_NBLK, 256, 0, stream>>>(counts, bsums);
    scan_pass_b<<<1, 512, 0, stream>>>(bsums);
    scan_pass_c<<<SCAN_NBLK, 256, 0, stream>>>(counts, bsums, col_start, cursor);

    // 4. scatter packed pre-scaled edges
    edge_scatter<<<(B_ * NNZ_ + 255) / 256, 256, 0, stream>>>(
        rows, cols, values, occ, cursor, pack);

    // 5. main accumulate + write-once
    mesh_unpool_main<<<B_ * NTILE, 256, 0, stream>>>(
        featT, pack, col_start, counts, out);
}